// Round 1
// baseline (485.833 us; speedup 1.0000x reference)
//
#include <hip/hip_runtime.h>
#include <hip/hip_bf16.h>

// Problem constants (TwoHopGATBlock)
#define BB 16
#define NN 1024
#define EE 32768
#define D_IN 33
#define HID 32
#define HEADS 4
#define OUTD 8
#define FF 32           // HEADS*OUTD
#define EPSL 1e-5f
#define SLOPE 0.2f

__device__ __forceinline__ float red32(float v) {
    v += __shfl_xor(v, 1);
    v += __shfl_xor(v, 2);
    v += __shfl_xor(v, 4);
    v += __shfl_xor(v, 8);
    v += __shfl_xor(v, 16);
    return v;
}
__device__ __forceinline__ float red8(float v) {
    v += __shfl_xor(v, 1);
    v += __shfl_xor(v, 2);
    v += __shfl_xor(v, 4);
    return v;
}

// ---------------- K0: zero A (256 MiB) + zero deg histogram ----------------
__global__ __launch_bounds__(256) void k_zero(float4* __restrict__ A4, int n4,
                                              int* __restrict__ deg) {
    int i = blockIdx.x * 256 + threadIdx.x;
    if (i < NN) deg[i] = 0;
    float4 z = make_float4(0.f, 0.f, 0.f, 0.f);
    int stride = gridDim.x * 256;
    for (int k = i; k < n4; k += stride) A4[k] = z;
}

// ---------------- CSR build: count / scan / fill ----------------
__global__ __launch_bounds__(256) void k_count(const int* __restrict__ ei,
                                               int* __restrict__ deg) {
    int e = blockIdx.x * 256 + threadIdx.x;
    if (e < EE) atomicAdd(&deg[ei[EE + e]], 1);
}

__global__ __launch_bounds__(1024) void k_scan(const int* __restrict__ deg,
                                               int* __restrict__ off,
                                               int* __restrict__ cur) {
    __shared__ int tmp[NN];
    int t = threadIdx.x;
    tmp[t] = deg[t];
    __syncthreads();
    for (int s = 1; s < NN; s <<= 1) {
        int v = (t >= s) ? tmp[t - s] : 0;
        __syncthreads();
        tmp[t] += v;
        __syncthreads();
    }
    off[t + 1] = tmp[t];
    int ex = (t == 0) ? 0 : tmp[t - 1];
    if (t == 0) off[0] = 0;
    cur[t] = ex;
}

__global__ __launch_bounds__(256) void k_fill(const int* __restrict__ ei,
                                              int* __restrict__ cur,
                                              int* __restrict__ csr_src) {
    int e = blockIdx.x * 256 + threadIdx.x;
    if (e < EE) {
        int d = ei[EE + e];
        int p = atomicAdd(&cur[d], 1);
        csr_src[p] = ei[e];
    }
}

// ---------------- K1: embedding MLP + LN + xp1 + attention logits ----------------
// 32 lanes per node, 8 nodes per 256-thread block. grid = B*N/8 = 2048
__global__ __launch_bounds__(256) void k_embed(
    const float* __restrict__ Hm, const float* __restrict__ W1,
    const float* __restrict__ b1, const float* __restrict__ W2,
    const float* __restrict__ b2, const float* __restrict__ lng,
    const float* __restrict__ lnb, const float* __restrict__ Wg1,
    const float* __restrict__ as1, const float* __restrict__ ad1,
    float* __restrict__ xp1, float* __restrict__ als1, float* __restrict__ ald1) {
    __shared__ float sW1[D_IN * 32];
    __shared__ float sW2[32 * 32];
    __shared__ float sWg[32 * 32];
    __shared__ float sb1[32], sb2[32], sg[32], sbt[32], sas[32], sad[32];
    __shared__ float sh[8][34];
    __shared__ float sx[8][33];
    int tid = threadIdx.x;
    for (int i = tid; i < D_IN * 32; i += 256) sW1[i] = W1[i];
    for (int i = tid; i < 1024; i += 256) { sW2[i] = W2[i]; sWg[i] = Wg1[i]; }
    if (tid < 32) {
        sb1[tid] = b1[tid]; sb2[tid] = b2[tid];
        sg[tid] = lng[tid]; sbt[tid] = lnb[tid];
        sas[tid] = as1[tid]; sad[tid] = ad1[tid];
    }
    int g = tid >> 5, j = tid & 31;
    int idx = blockIdx.x * 8 + g;   // b*N + n
    __syncthreads();
    int base = idx * D_IN;
    for (int i = j; i < D_IN; i += 32) sh[g][i] = Hm[base + i];
    __syncthreads();
    float acc = sb1[j];
#pragma unroll
    for (int i = 0; i < D_IN; i++) acc += sh[g][i] * sW1[i * 32 + j];
    float x1 = fmaxf(acc, 0.f);
    sx[g][j] = x1;
    __syncthreads();
    acc = sb2[j];
#pragma unroll
    for (int i = 0; i < 32; i++) acc += sx[g][i] * sW2[i * 32 + j];
    float x2 = fmaxf(acc, 0.f);
    float mean = red32(x2) * (1.f / 32.f);
    float d0 = x2 - mean;
    float var = red32(d0 * d0) * (1.f / 32.f);
    float xn = d0 * rsqrtf(var + EPSL) * sg[j] + sbt[j];
    __syncthreads();
    sx[g][j] = xn;
    __syncthreads();
    acc = 0.f;
#pragma unroll
    for (int i = 0; i < 32; i++) acc += sx[g][i] * sWg[i * 32 + j];
    xp1[idx * 32 + j] = acc;
    float ps = red8(acc * sas[j]);
    float pd = red8(acc * sad[j]);
    if ((j & 7) == 0) {
        als1[idx * 4 + (j >> 3)] = ps;
        ald1[idx * 4 + (j >> 3)] = pd;
    }
}

// ---------------- K2: GAT layer 1 gather + h1 + xp2 + logits2 ----------------
__global__ __launch_bounds__(256) void k_gat1(
    const int* __restrict__ off, const int* __restrict__ csr_src,
    const float* __restrict__ xp1, const float* __restrict__ als1,
    const float* __restrict__ ald1, const float* __restrict__ bi1,
    const float* __restrict__ Wg2, const float* __restrict__ as2,
    const float* __restrict__ ad2, float* __restrict__ h1,
    float* __restrict__ xp2, float* __restrict__ als2, float* __restrict__ ald2) {
    __shared__ float sW[1024];
    __shared__ float sb[32], sas[32], sad[32];
    __shared__ float sx[8][33];
    int tid = threadIdx.x;
    for (int i = tid; i < 1024; i += 256) sW[i] = Wg2[i];
    if (tid < 32) { sb[tid] = bi1[tid]; sas[tid] = as2[tid]; sad[tid] = ad2[tid]; }
    __syncthreads();
    int g = tid >> 5, j = tid & 31, h = j >> 3;
    int idx = blockIdx.x * 8 + g;
    int b = idx >> 10, n = idx & 1023;
    int beg = off[n], end = off[n + 1];
    float aldh = ald1[idx * 4 + h];
    const float* alsb = als1 + b * NN * 4;
    float se = 0.f;
    for (int k = beg; k < end; k++) {
        int s = csr_src[k];
        float av = alsb[s * 4 + h] + aldh;
        av = av > 0.f ? av : SLOPE * av;
        se += __expf(av);
    }
    float inv = se > 0.f ? 1.f / se : 0.f;
    const float* xpb = xp1 + b * NN * 32;
    float acc = 0.f;
    for (int k = beg; k < end; k++) {
        int s = csr_src[k];
        float av = alsb[s * 4 + h] + aldh;
        av = av > 0.f ? av : SLOPE * av;
        acc += __expf(av) * inv * xpb[s * 32 + j];
    }
    float hv = fmaxf(acc + sb[j], 0.f);
    h1[idx * 32 + j] = hv;
    sx[g][j] = hv;
    __syncthreads();
    float x2 = 0.f;
#pragma unroll
    for (int i = 0; i < 32; i++) x2 += sx[g][i] * sW[i * 32 + j];
    xp2[idx * 32 + j] = x2;
    float ps = red8(x2 * sas[j]);
    float pd = red8(x2 * sad[j]);
    if ((j & 7) == 0) { als2[idx * 4 + h] = ps; ald2[idx * 4 + h] = pd; }
}

// ---------------- K3: GAT layer 2 gather + A scatter + output LN ----------------
__global__ __launch_bounds__(256) void k_gat2(
    const int* __restrict__ off, const int* __restrict__ csr_src,
    const float* __restrict__ xp2, const float* __restrict__ als2,
    const float* __restrict__ ald2, const float* __restrict__ h1,
    const float* __restrict__ bi2, const float* __restrict__ lng,
    const float* __restrict__ lnb, float* __restrict__ outH,
    float* __restrict__ A) {
    __shared__ float sb[32], sg[32], sbt[32];
    int tid = threadIdx.x;
    if (tid < 32) { sb[tid] = bi2[tid]; sg[tid] = lng[tid]; sbt[tid] = lnb[tid]; }
    __syncthreads();
    int g = tid >> 5, j = tid & 31, h = j >> 3, dl = j & 7;
    int idx = blockIdx.x * 8 + g;
    int b = idx >> 10, n = idx & 1023;
    int beg = off[n], end = off[n + 1];
    float aldh = ald2[idx * 4 + h];
    const float* alsb = als2 + b * NN * 4;
    float se = 0.f;
    for (int k = beg; k < end; k++) {
        int s = csr_src[k];
        float av = alsb[s * 4 + h] + aldh;
        av = av > 0.f ? av : SLOPE * av;
        se += __expf(av);
    }
    float inv = se > 0.f ? 1.f / se : 0.f;
    const float* xpb = xp2 + b * NN * 32;
    float* Abh = A + (b * 4 + h) * (NN * NN);
    float acc = 0.f;
    for (int k = beg; k < end; k++) {
        int s = csr_src[k];
        float av = alsb[s * 4 + h] + aldh;
        av = av > 0.f ? av : SLOPE * av;
        float al = __expf(av) * inv;
        acc += al * xpb[s * 32 + j];
        if (dl == 0) Abh[s * NN + n] = al;
    }
    float y = h1[idx * 32 + j] + acc + sb[j];
    float mean = red32(y) * (1.f / 32.f);
    float d0 = y - mean;
    float var = red32(d0 * d0) * (1.f / 32.f);
    outH[idx * 32 + j] = d0 * rsqrtf(var + EPSL) * sg[j] + sbt[j];
}

extern "C" void kernel_launch(void* const* d_in, const int* in_sizes, int n_in,
                              void* d_out, int out_size, void* d_ws, size_t ws_size,
                              hipStream_t stream) {
    const float* Hm  = (const float*)d_in[0];
    const int*   ei  = (const int*)d_in[1];
    const float* W1  = (const float*)d_in[2];
    const float* b1  = (const float*)d_in[3];
    const float* W2  = (const float*)d_in[4];
    const float* b2  = (const float*)d_in[5];
    const float* lneg = (const float*)d_in[6];
    const float* lneb = (const float*)d_in[7];
    const float* Wg1 = (const float*)d_in[8];
    const float* as1 = (const float*)d_in[9];
    const float* ad1 = (const float*)d_in[10];
    const float* bi1 = (const float*)d_in[11];
    const float* Wg2 = (const float*)d_in[12];
    const float* as2 = (const float*)d_in[13];
    const float* ad2 = (const float*)d_in[14];
    const float* bi2 = (const float*)d_in[15];
    const float* lnog = (const float*)d_in[16];
    const float* lnob = (const float*)d_in[17];

    float* outH = (float*)d_out;                 // [B,N,32] = 524288 floats
    float* A    = outH + BB * NN * FF;           // [B,4,N,N] = 67108864 floats

    // workspace carve (ints first, then floats; all within d_ws)
    int* deg = (int*)d_ws;              // 1024
    int* off = deg + 1024;              // 1025
    int* cur = off + 1028;              // 1024
    int* csr_src = cur + 1024;          // 32768
    float* fb = (float*)(csr_src + EE);
    // pad to 16B alignment (already aligned: (1024+1028+1024+32768)*4 bytes)
    float* xp1  = fb;                   // 524288
    float* als1 = xp1 + BB * NN * FF;   // 65536
    float* ald1 = als1 + BB * NN * 4;   // 65536
    float* h1   = ald1 + BB * NN * 4;   // 524288
    float* xp2  = h1 + BB * NN * FF;    // 524288
    float* als2 = xp2 + BB * NN * FF;   // 65536
    float* ald2 = als2 + BB * NN * 4;   // 65536

    int n4 = (BB * HEADS * NN * NN) / 4;  // 16777216 float4s
    hipLaunchKernelGGL(k_zero, dim3(4096), dim3(256), 0, stream, (float4*)A, n4, deg);
    hipLaunchKernelGGL(k_count, dim3(EE / 256), dim3(256), 0, stream, ei, deg);
    hipLaunchKernelGGL(k_scan, dim3(1), dim3(1024), 0, stream, deg, off, cur);
    hipLaunchKernelGGL(k_fill, dim3(EE / 256), dim3(256), 0, stream, ei, cur, csr_src);
    hipLaunchKernelGGL(k_embed, dim3(BB * NN / 8), dim3(256), 0, stream,
                       Hm, W1, b1, W2, b2, lneg, lneb, Wg1, as1, ad1,
                       xp1, als1, ald1);
    hipLaunchKernelGGL(k_gat1, dim3(BB * NN / 8), dim3(256), 0, stream,
                       off, csr_src, xp1, als1, ald1, bi1, Wg2, as2, ad2,
                       h1, xp2, als2, ald2);
    hipLaunchKernelGGL(k_gat2, dim3(BB * NN / 8), dim3(256), 0, stream,
                       off, csr_src, xp2, als2, ald2, h1, bi2, lnog, lnob,
                       outH, A);
}

// Round 2
// 409.334 us; speedup vs baseline: 1.1869x; 1.1869x over previous
//
#include <hip/hip_runtime.h>
#include <hip/hip_bf16.h>

// Problem constants (TwoHopGATBlock)
#define BB 16
#define NN 1024
#define EE 32768
#define D_IN 33
#define HID 32
#define HEADS 4
#define OUTD 8
#define FF 32           // HEADS*OUTD
#define EPSL 1e-5f
#define SLOPE 0.2f

__device__ __forceinline__ float red32(float v) {
    v += __shfl_xor(v, 1);
    v += __shfl_xor(v, 2);
    v += __shfl_xor(v, 4);
    v += __shfl_xor(v, 8);
    v += __shfl_xor(v, 16);
    return v;
}
__device__ __forceinline__ float red8(float v) {
    v += __shfl_xor(v, 1);
    v += __shfl_xor(v, 2);
    v += __shfl_xor(v, 4);
    return v;
}

// ---------------- K_init: zero degree histograms ----------------
__global__ __launch_bounds__(256) void k_init(int* __restrict__ deg,
                                              int* __restrict__ deg2) {
    int i = threadIdx.x;
    for (int k = i; k < NN; k += 256) { deg[k] = 0; deg2[k] = 0; }
}

// ---------------- CSR build: count / scan / fill (both directions) -------
__global__ __launch_bounds__(256) void k_count(const int* __restrict__ ei,
                                               int* __restrict__ deg,
                                               int* __restrict__ deg2) {
    int e = blockIdx.x * 256 + threadIdx.x;
    if (e < EE) {
        atomicAdd(&deg[ei[EE + e]], 1);   // by dst (in-CSR)
        atomicAdd(&deg2[ei[e]], 1);       // by src (out-CSR)
    }
}

__global__ __launch_bounds__(1024) void k_scan(
    const int* __restrict__ deg, int* __restrict__ off, int* __restrict__ cur,
    const int* __restrict__ deg2, int* __restrict__ off2, int* __restrict__ cur2) {
    __shared__ int tmp[NN];
    int t = threadIdx.x;
    // scan 1 (in-CSR by dst)
    tmp[t] = deg[t];
    __syncthreads();
    for (int s = 1; s < NN; s <<= 1) {
        int v = (t >= s) ? tmp[t - s] : 0;
        __syncthreads();
        tmp[t] += v;
        __syncthreads();
    }
    off[t + 1] = tmp[t];
    if (t == 0) off[0] = 0;
    cur[t] = (t == 0) ? 0 : tmp[t - 1];
    __syncthreads();
    // scan 2 (out-CSR by src)
    tmp[t] = deg2[t];
    __syncthreads();
    for (int s = 1; s < NN; s <<= 1) {
        int v = (t >= s) ? tmp[t - s] : 0;
        __syncthreads();
        tmp[t] += v;
        __syncthreads();
    }
    off2[t + 1] = tmp[t];
    if (t == 0) off2[0] = 0;
    cur2[t] = (t == 0) ? 0 : tmp[t - 1];
}

__global__ __launch_bounds__(256) void k_fill(const int* __restrict__ ei,
                                              int* __restrict__ cur,
                                              int* __restrict__ csr_src,
                                              int* __restrict__ csr_eid,
                                              int* __restrict__ cur2,
                                              int* __restrict__ out_dst,
                                              int* __restrict__ out_eid) {
    int e = blockIdx.x * 256 + threadIdx.x;
    if (e < EE) {
        int s = ei[e], d = ei[EE + e];
        int p = atomicAdd(&cur[d], 1);
        csr_src[p] = s;
        csr_eid[p] = e;
        int p2 = atomicAdd(&cur2[s], 1);
        out_dst[p2] = d;
        out_eid[p2] = e;
    }
}

// ---------------- K1: embedding MLP + LN + xp1 + attention logits --------
// 32 lanes per node, 8 nodes per 256-thread block. grid = B*N/8 = 2048
__global__ __launch_bounds__(256) void k_embed(
    const float* __restrict__ Hm, const float* __restrict__ W1,
    const float* __restrict__ b1, const float* __restrict__ W2,
    const float* __restrict__ b2, const float* __restrict__ lng,
    const float* __restrict__ lnb, const float* __restrict__ Wg1,
    const float* __restrict__ as1, const float* __restrict__ ad1,
    float* __restrict__ xp1, float* __restrict__ als1, float* __restrict__ ald1) {
    __shared__ float sW1[D_IN * 32];
    __shared__ float sW2[32 * 32];
    __shared__ float sWg[32 * 32];
    __shared__ float sb1[32], sb2[32], sg[32], sbt[32], sas[32], sad[32];
    __shared__ float sh[8][34];
    __shared__ float sx[8][33];
    int tid = threadIdx.x;
    for (int i = tid; i < D_IN * 32; i += 256) sW1[i] = W1[i];
    for (int i = tid; i < 1024; i += 256) { sW2[i] = W2[i]; sWg[i] = Wg1[i]; }
    if (tid < 32) {
        sb1[tid] = b1[tid]; sb2[tid] = b2[tid];
        sg[tid] = lng[tid]; sbt[tid] = lnb[tid];
        sas[tid] = as1[tid]; sad[tid] = ad1[tid];
    }
    int g = tid >> 5, j = tid & 31;
    int idx = blockIdx.x * 8 + g;   // b*N + n
    __syncthreads();
    int base = idx * D_IN;
    for (int i = j; i < D_IN; i += 32) sh[g][i] = Hm[base + i];
    __syncthreads();
    float acc = sb1[j];
#pragma unroll
    for (int i = 0; i < D_IN; i++) acc += sh[g][i] * sW1[i * 32 + j];
    float x1 = fmaxf(acc, 0.f);
    sx[g][j] = x1;
    __syncthreads();
    acc = sb2[j];
#pragma unroll
    for (int i = 0; i < 32; i++) acc += sx[g][i] * sW2[i * 32 + j];
    float x2 = fmaxf(acc, 0.f);
    float mean = red32(x2) * (1.f / 32.f);
    float d0 = x2 - mean;
    float var = red32(d0 * d0) * (1.f / 32.f);
    float xn = d0 * rsqrtf(var + EPSL) * sg[j] + sbt[j];
    __syncthreads();
    sx[g][j] = xn;
    __syncthreads();
    acc = 0.f;
#pragma unroll
    for (int i = 0; i < 32; i++) acc += sx[g][i] * sWg[i * 32 + j];
    xp1[idx * 32 + j] = acc;
    float ps = red8(acc * sas[j]);
    float pd = red8(acc * sad[j]);
    if ((j & 7) == 0) {
        als1[idx * 4 + (j >> 3)] = ps;
        ald1[idx * 4 + (j >> 3)] = pd;
    }
}

// ---------------- K2: GAT layer 1 gather + h1 + xp2 + logits2 ------------
__global__ __launch_bounds__(256) void k_gat1(
    const int* __restrict__ off, const int* __restrict__ csr_src,
    const float* __restrict__ xp1, const float* __restrict__ als1,
    const float* __restrict__ ald1, const float* __restrict__ bi1,
    const float* __restrict__ Wg2, const float* __restrict__ as2,
    const float* __restrict__ ad2, float* __restrict__ h1,
    float* __restrict__ xp2, float* __restrict__ als2, float* __restrict__ ald2) {
    __shared__ float sW[1024];
    __shared__ float sb[32], sas[32], sad[32];
    __shared__ float sx[8][33];
    int tid = threadIdx.x;
    for (int i = tid; i < 1024; i += 256) sW[i] = Wg2[i];
    if (tid < 32) { sb[tid] = bi1[tid]; sas[tid] = as2[tid]; sad[tid] = ad2[tid]; }
    __syncthreads();
    int g = tid >> 5, j = tid & 31, h = j >> 3, lane8 = j & 7;
    int idx = blockIdx.x * 8 + g;
    int b = idx >> 10, n = idx & 1023;
    int beg = off[n], end = off[n + 1];
    float aldh = ald1[idx * 4 + h];
    const float* alsb = als1 + b * NN * 4;
    // pass 1: softmax denominator, edges split 8-way within each head group
    float se = 0.f;
    for (int k = beg + lane8; k < end; k += 8) {
        int s = csr_src[k];
        float av = alsb[s * 4 + h] + aldh;
        av = av > 0.f ? av : SLOPE * av;
        se += __expf(av);
    }
    se = red8(se);
    float inv = se > 0.f ? 1.f / se : 0.f;
    // pass 2: alpha computed once per (head, edge), broadcast via shfl
    const float* xpb = xp1 + b * NN * 32;
    float acc = 0.f;
    for (int kb = beg; kb < end; kb += 8) {
        int k = kb + lane8;
        float al = 0.f;
        int s = 0;
        if (k < end) {
            s = csr_src[k];
            float av = alsb[s * 4 + h] + aldh;
            av = av > 0.f ? av : SLOPE * av;
            al = __expf(av) * inv;
        }
        int lim = end - kb; if (lim > 8) lim = 8;
        for (int t = 0; t < lim; t++) {
            int st = __shfl(s, t, 32);                 // same s for all heads
            float alt = __shfl(al, (h << 3) + t, 32);  // head-specific alpha
            acc += alt * xpb[st * 32 + j];
        }
    }
    float hv = fmaxf(acc + sb[j], 0.f);
    h1[idx * 32 + j] = hv;
    sx[g][j] = hv;
    __syncthreads();
    float x2 = 0.f;
#pragma unroll
    for (int i = 0; i < 32; i++) x2 += sx[g][i] * sW[i * 32 + j];
    xp2[idx * 32 + j] = x2;
    float ps = red8(x2 * sas[j]);
    float pd = red8(x2 * sad[j]);
    if ((j & 7) == 0) { als2[idx * 4 + h] = ps; ald2[idx * 4 + h] = pd; }
}

// ------- K3: GAT layer 2 gather + alphaE emit + residual + output LN -----
__global__ __launch_bounds__(256) void k_gat2(
    const int* __restrict__ off, const int* __restrict__ csr_src,
    const int* __restrict__ csr_eid, const float* __restrict__ xp2,
    const float* __restrict__ als2, const float* __restrict__ ald2,
    const float* __restrict__ h1, const float* __restrict__ bi2,
    const float* __restrict__ lng, const float* __restrict__ lnb,
    float* __restrict__ outH, float* __restrict__ alphaE) {
    __shared__ float sb[32], sg[32], sbt[32];
    int tid = threadIdx.x;
    if (tid < 32) { sb[tid] = bi2[tid]; sg[tid] = lng[tid]; sbt[tid] = lnb[tid]; }
    __syncthreads();
    int g = tid >> 5, j = tid & 31, h = j >> 3, lane8 = j & 7;
    int idx = blockIdx.x * 8 + g;
    int b = idx >> 10, n = idx & 1023;
    int beg = off[n], end = off[n + 1];
    float aldh = ald2[idx * 4 + h];
    const float* alsb = als2 + b * NN * 4;
    float se = 0.f;
    for (int k = beg + lane8; k < end; k += 8) {
        int s = csr_src[k];
        float av = alsb[s * 4 + h] + aldh;
        av = av > 0.f ? av : SLOPE * av;
        se += __expf(av);
    }
    se = red8(se);
    float inv = se > 0.f ? 1.f / se : 0.f;
    const float* xpb = xp2 + b * NN * 32;
    float* aEb = alphaE + (size_t)b * 4 * EE + (size_t)h * EE;
    float acc = 0.f;
    for (int kb = beg; kb < end; kb += 8) {
        int k = kb + lane8;
        float al = 0.f;
        int s = 0;
        if (k < end) {
            s = csr_src[k];
            float av = alsb[s * 4 + h] + aldh;
            av = av > 0.f ? av : SLOPE * av;
            al = __expf(av) * inv;
            aEb[csr_eid[k]] = al;   // compact per-edge alpha (one store per head,edge)
        }
        int lim = end - kb; if (lim > 8) lim = 8;
        for (int t = 0; t < lim; t++) {
            int st = __shfl(s, t, 32);
            float alt = __shfl(al, (h << 3) + t, 32);
            acc += alt * xpb[st * 32 + j];
        }
    }
    float y = h1[idx * 32 + j] + acc + sb[j];
    float mean = red32(y) * (1.f / 32.f);
    float d0 = y - mean;
    float var = red32(d0 * d0) * (1.f / 32.f);
    outH[idx * 32 + j] = d0 * rsqrtf(var + EPSL) * sg[j] + sbt[j];
}

// ------- K4: compose A rows in LDS, stream out (A written exactly once) --
#define ROWS_PER_BLOCK 4
__global__ __launch_bounds__(256) void k_rowA(
    const int* __restrict__ off2, const int* __restrict__ out_dst,
    const int* __restrict__ out_eid, const float* __restrict__ alphaE,
    float* __restrict__ A) {
    __shared__ float sRow[ROWS_PER_BLOCK][NN];
    int wid = threadIdx.x >> 6, lane = threadIdx.x & 63;
    int r = blockIdx.x * ROWS_PER_BLOCK + wid;   // 0..65535 = (b*4+h)*1024 + src
    int bh = r >> 10, src = r & 1023;
    float4* row4 = (float4*)&sRow[wid][0];
    float4 z = make_float4(0.f, 0.f, 0.f, 0.f);
#pragma unroll
    for (int i = 0; i < 4; i++) row4[i * 64 + lane] = z;
    __syncthreads();
    int beg = off2[src], end = off2[src + 1];
    const float* aE = alphaE + (size_t)bh * EE;
    for (int p = beg + lane; p < end; p += 64) {
        sRow[wid][out_dst[p]] = aE[out_eid[p]];
    }
    __syncthreads();
    float4* o4 = (float4*)(A + (size_t)bh * (NN * NN) + (size_t)src * NN);
#pragma unroll
    for (int i = 0; i < 4; i++) o4[i * 64 + lane] = row4[i * 64 + lane];
}

extern "C" void kernel_launch(void* const* d_in, const int* in_sizes, int n_in,
                              void* d_out, int out_size, void* d_ws, size_t ws_size,
                              hipStream_t stream) {
    const float* Hm  = (const float*)d_in[0];
    const int*   ei  = (const int*)d_in[1];
    const float* W1  = (const float*)d_in[2];
    const float* b1  = (const float*)d_in[3];
    const float* W2  = (const float*)d_in[4];
    const float* b2  = (const float*)d_in[5];
    const float* lneg = (const float*)d_in[6];
    const float* lneb = (const float*)d_in[7];
    const float* Wg1 = (const float*)d_in[8];
    const float* as1 = (const float*)d_in[9];
    const float* ad1 = (const float*)d_in[10];
    const float* bi1 = (const float*)d_in[11];
    const float* Wg2 = (const float*)d_in[12];
    const float* as2 = (const float*)d_in[13];
    const float* ad2 = (const float*)d_in[14];
    const float* bi2 = (const float*)d_in[15];
    const float* lnog = (const float*)d_in[16];
    const float* lnob = (const float*)d_in[17];

    float* outH = (float*)d_out;                 // [B,N,32] = 524288 floats
    float* A    = outH + BB * NN * FF;           // [B,4,N,N] = 67108864 floats

    // workspace carve
    int* deg     = (int*)d_ws;          // 1024
    int* off     = deg + 1024;          // 1028 (1025 used)
    int* cur     = off + 1028;          // 1024
    int* deg2    = cur + 1024;          // 1024
    int* off2    = deg2 + 1024;         // 1028
    int* cur2    = off2 + 1028;         // 1024
    int* csr_src = cur2 + 1024;         // 32768
    int* csr_eid = csr_src + EE;        // 32768
    int* out_dst = csr_eid + EE;        // 32768
    int* out_eid = out_dst + EE;        // 32768
    float* fb    = (float*)(out_eid + EE);
    float* xp1    = fb;                  // 524288
    float* als1   = xp1 + BB * NN * FF;  // 65536
    float* ald1   = als1 + BB * NN * 4;  // 65536
    float* h1     = ald1 + BB * NN * 4;  // 524288
    float* xp2    = h1 + BB * NN * FF;   // 524288
    float* als2   = xp2 + BB * NN * FF;  // 65536
    float* ald2   = als2 + BB * NN * 4;  // 65536
    float* alphaE = ald2 + BB * NN * 4;  // 2097152 (B*H*E)

    hipLaunchKernelGGL(k_init, dim3(1), dim3(256), 0, stream, deg, deg2);
    hipLaunchKernelGGL(k_count, dim3(EE / 256), dim3(256), 0, stream, ei, deg, deg2);
    hipLaunchKernelGGL(k_scan, dim3(1), dim3(1024), 0, stream,
                       deg, off, cur, deg2, off2, cur2);
    hipLaunchKernelGGL(k_fill, dim3(EE / 256), dim3(256), 0, stream,
                       ei, cur, csr_src, csr_eid, cur2, out_dst, out_eid);
    hipLaunchKernelGGL(k_embed, dim3(BB * NN / 8), dim3(256), 0, stream,
                       Hm, W1, b1, W2, b2, lneg, lneb, Wg1, as1, ad1,
                       xp1, als1, ald1);
    hipLaunchKernelGGL(k_gat1, dim3(BB * NN / 8), dim3(256), 0, stream,
                       off, csr_src, xp1, als1, ald1, bi1, Wg2, as2, ad2,
                       h1, xp2, als2, ald2);
    hipLaunchKernelGGL(k_gat2, dim3(BB * NN / 8), dim3(256), 0, stream,
                       off, csr_src, csr_eid, xp2, als2, ald2, h1, bi2, lnog, lnob,
                       outH, alphaE);
    hipLaunchKernelGGL(k_rowA, dim3(BB * HEADS * NN / ROWS_PER_BLOCK), dim3(256),
                       0, stream, off2, out_dst, out_eid, alphaE, A);
}

// Round 3
// 396.331 us; speedup vs baseline: 1.2258x; 1.0328x over previous
//
#include <hip/hip_runtime.h>
#include <hip/hip_bf16.h>

// Problem constants (TwoHopGATBlock)
#define BB 16
#define NN 1024
#define EE 32768
#define D_IN 33
#define HID 32
#define HEADS 4
#define OUTD 8
#define FF 32           // HEADS*OUTD
#define EPSL 1e-5f
#define SLOPE 0.2f

__device__ __forceinline__ float red32(float v) {
    v += __shfl_xor(v, 1);
    v += __shfl_xor(v, 2);
    v += __shfl_xor(v, 4);
    v += __shfl_xor(v, 8);
    v += __shfl_xor(v, 16);
    return v;
}
__device__ __forceinline__ float red8(float v) {
    v += __shfl_xor(v, 1);
    v += __shfl_xor(v, 2);
    v += __shfl_xor(v, 4);
    return v;
}

// ---------------- K_init: zero degree histograms ----------------
__global__ __launch_bounds__(256) void k_init(int* __restrict__ deg,
                                              int* __restrict__ deg2) {
    int i = threadIdx.x;
    for (int k = i; k < NN; k += 256) { deg[k] = 0; deg2[k] = 0; }
}

// ---------------- CSR build: count / scan / fill (both directions) -------
__global__ __launch_bounds__(256) void k_count(const int* __restrict__ ei,
                                               int* __restrict__ deg,
                                               int* __restrict__ deg2) {
    int e = blockIdx.x * 256 + threadIdx.x;
    if (e < EE) {
        atomicAdd(&deg[ei[EE + e]], 1);   // by dst (in-CSR)
        atomicAdd(&deg2[ei[e]], 1);       // by src (out-CSR)
    }
}

__global__ __launch_bounds__(1024) void k_scan(
    const int* __restrict__ deg, int* __restrict__ off, int* __restrict__ cur,
    const int* __restrict__ deg2, int* __restrict__ off2, int* __restrict__ cur2) {
    __shared__ int tmp[NN];
    int t = threadIdx.x;
    tmp[t] = deg[t];
    __syncthreads();
    for (int s = 1; s < NN; s <<= 1) {
        int v = (t >= s) ? tmp[t - s] : 0;
        __syncthreads();
        tmp[t] += v;
        __syncthreads();
    }
    off[t + 1] = tmp[t];
    if (t == 0) off[0] = 0;
    cur[t] = (t == 0) ? 0 : tmp[t - 1];
    __syncthreads();
    tmp[t] = deg2[t];
    __syncthreads();
    for (int s = 1; s < NN; s <<= 1) {
        int v = (t >= s) ? tmp[t - s] : 0;
        __syncthreads();
        tmp[t] += v;
        __syncthreads();
    }
    off2[t + 1] = tmp[t];
    if (t == 0) off2[0] = 0;
    cur2[t] = (t == 0) ? 0 : tmp[t - 1];
}

__global__ __launch_bounds__(256) void k_fill(const int* __restrict__ ei,
                                              int* __restrict__ cur,
                                              int* __restrict__ csr_src,
                                              int* __restrict__ cur2,
                                              int* __restrict__ out_dst,
                                              int* __restrict__ csr_opos) {
    int e = blockIdx.x * 256 + threadIdx.x;
    if (e < EE) {
        int s = ei[e], d = ei[EE + e];
        int p = atomicAdd(&cur[d], 1);
        csr_src[p] = s;
        int p2 = atomicAdd(&cur2[s], 1);
        out_dst[p2] = d;
        csr_opos[p] = p2;   // in-CSR slot -> out-CSR slot
    }
}

// ---------------- K1: embedding MLP + LN + xp1 + attention logits --------
__global__ __launch_bounds__(256) void k_embed(
    const float* __restrict__ Hm, const float* __restrict__ W1,
    const float* __restrict__ b1, const float* __restrict__ W2,
    const float* __restrict__ b2, const float* __restrict__ lng,
    const float* __restrict__ lnb, const float* __restrict__ Wg1,
    const float* __restrict__ as1, const float* __restrict__ ad1,
    float* __restrict__ xp1, float* __restrict__ als1, float* __restrict__ ald1) {
    __shared__ float sW1[D_IN * 32];
    __shared__ float sW2[32 * 32];
    __shared__ float sWg[32 * 32];
    __shared__ float sb1[32], sb2[32], sg[32], sbt[32], sas[32], sad[32];
    __shared__ float sh[8][34];
    __shared__ float sx[8][33];
    int tid = threadIdx.x;
    for (int i = tid; i < D_IN * 32; i += 256) sW1[i] = W1[i];
    for (int i = tid; i < 1024; i += 256) { sW2[i] = W2[i]; sWg[i] = Wg1[i]; }
    if (tid < 32) {
        sb1[tid] = b1[tid]; sb2[tid] = b2[tid];
        sg[tid] = lng[tid]; sbt[tid] = lnb[tid];
        sas[tid] = as1[tid]; sad[tid] = ad1[tid];
    }
    int g = tid >> 5, j = tid & 31;
    int idx = blockIdx.x * 8 + g;   // b*N + n
    __syncthreads();
    int base = idx * D_IN;
    for (int i = j; i < D_IN; i += 32) sh[g][i] = Hm[base + i];
    __syncthreads();
    float acc = sb1[j];
#pragma unroll
    for (int i = 0; i < D_IN; i++) acc += sh[g][i] * sW1[i * 32 + j];
    float x1 = fmaxf(acc, 0.f);
    sx[g][j] = x1;
    __syncthreads();
    acc = sb2[j];
#pragma unroll
    for (int i = 0; i < 32; i++) acc += sx[g][i] * sW2[i * 32 + j];
    float x2 = fmaxf(acc, 0.f);
    float mean = red32(x2) * (1.f / 32.f);
    float d0 = x2 - mean;
    float var = red32(d0 * d0) * (1.f / 32.f);
    float xn = d0 * rsqrtf(var + EPSL) * sg[j] + sbt[j];
    __syncthreads();
    sx[g][j] = xn;
    __syncthreads();
    acc = 0.f;
#pragma unroll
    for (int i = 0; i < 32; i++) acc += sx[g][i] * sWg[i * 32 + j];
    xp1[idx * 32 + j] = acc;
    float ps = red8(acc * sas[j]);
    float pd = red8(acc * sad[j]);
    if ((j & 7) == 0) {
        als1[idx * 4 + (j >> 3)] = ps;
        ald1[idx * 4 + (j >> 3)] = pd;
    }
}

// ---------------- K2: GAT layer 1 gather + h1 + xp2 + logits2 ------------
__global__ __launch_bounds__(256) void k_gat1(
    const int* __restrict__ off, const int* __restrict__ csr_src,
    const float* __restrict__ xp1, const float* __restrict__ als1,
    const float* __restrict__ ald1, const float* __restrict__ bi1,
    const float* __restrict__ Wg2, const float* __restrict__ as2,
    const float* __restrict__ ad2, float* __restrict__ h1,
    float* __restrict__ xp2, float* __restrict__ als2, float* __restrict__ ald2) {
    __shared__ float sW[1024];
    __shared__ float sb[32], sas[32], sad[32];
    __shared__ float sx[8][33];
    __shared__ float salp[8][32];   // [node][h*8+t]
    __shared__ int   ssrc[8][8];
    int tid = threadIdx.x;
    for (int i = tid; i < 1024; i += 256) sW[i] = Wg2[i];
    if (tid < 32) { sb[tid] = bi1[tid]; sas[tid] = as2[tid]; sad[tid] = ad2[tid]; }
    __syncthreads();
    int g = tid >> 5, j = tid & 31, h = j >> 3, t8 = j & 7;
    int idx = blockIdx.x * 8 + g;
    int b = idx >> 10, n = idx & 1023;
    int beg = off[n], end = off[n + 1];
    float aldh = ald1[idx * 4 + h];
    const float* alsb = als1 + b * NN * 4;
    // pass 1: softmax denominator, edges split 8-way within each head group
    float se = 0.f;
    for (int k = beg + t8; k < end; k += 8) {
        int s = csr_src[k];
        float av = alsb[s * 4 + h] + aldh;
        av = av > 0.f ? av : SLOPE * av;
        se += __expf(av);
    }
    se = red8(se);
    float inv = se > 0.f ? 1.f / se : 0.f;
    // pass 2: alphas staged in LDS, unrolled 8-wide gather (independent loads)
    const float* xpb = xp1 + b * NN * 32;
    float acc = 0.f;
    for (int kb = beg; kb < end; kb += 8) {
        int k = kb + t8;
        float al = 0.f; int s = 0;
        if (k < end) {
            s = csr_src[k];
            float av = alsb[s * 4 + h] + aldh;
            av = av > 0.f ? av : SLOPE * av;
            al = __expf(av) * inv;
        }
        salp[g][j] = al;
        if (h == 0) ssrc[g][t8] = s;
        __builtin_amdgcn_wave_barrier();
#pragma unroll
        for (int t = 0; t < 8; t++)
            acc += salp[g][(h << 3) + t] * xpb[ssrc[g][t] * 32 + j];
        __builtin_amdgcn_wave_barrier();
    }
    float hv = fmaxf(acc + sb[j], 0.f);
    h1[idx * 32 + j] = hv;
    sx[g][j] = hv;
    __syncthreads();
    float x2 = 0.f;
#pragma unroll
    for (int i = 0; i < 32; i++) x2 += sx[g][i] * sW[i * 32 + j];
    xp2[idx * 32 + j] = x2;
    float ps = red8(x2 * sas[j]);
    float pd = red8(x2 * sad[j]);
    if ((j & 7) == 0) { als2[idx * 4 + h] = ps; ald2[idx * 4 + h] = pd; }
}

// ------- K3: GAT layer 2 gather + alphaE emit + residual + output LN -----
__global__ __launch_bounds__(256) void k_gat2(
    const int* __restrict__ off, const int* __restrict__ csr_src,
    const int* __restrict__ csr_opos, const float* __restrict__ xp2,
    const float* __restrict__ als2, const float* __restrict__ ald2,
    const float* __restrict__ h1, const float* __restrict__ bi2,
    const float* __restrict__ lng, const float* __restrict__ lnb,
    float* __restrict__ outH, float* __restrict__ alphaE) {
    __shared__ float sb[32], sg[32], sbt[32];
    __shared__ float salp[8][32];
    __shared__ int   ssrc[8][8];
    int tid = threadIdx.x;
    if (tid < 32) { sb[tid] = bi2[tid]; sg[tid] = lng[tid]; sbt[tid] = lnb[tid]; }
    __syncthreads();
    int g = tid >> 5, j = tid & 31, h = j >> 3, t8 = j & 7;
    int idx = blockIdx.x * 8 + g;
    int b = idx >> 10, n = idx & 1023;
    int beg = off[n], end = off[n + 1];
    float aldh = ald2[idx * 4 + h];
    const float* alsb = als2 + b * NN * 4;
    float se = 0.f;
    for (int k = beg + t8; k < end; k += 8) {
        int s = csr_src[k];
        float av = alsb[s * 4 + h] + aldh;
        av = av > 0.f ? av : SLOPE * av;
        se += __expf(av);
    }
    se = red8(se);
    float inv = se > 0.f ? 1.f / se : 0.f;
    const float* xpb = xp2 + b * NN * 32;
    float* aEb = alphaE + ((size_t)b * 4 + h) * EE;
    float acc = 0.f;
    for (int kb = beg; kb < end; kb += 8) {
        int k = kb + t8;
        float al = 0.f; int s = 0;
        if (k < end) {
            s = csr_src[k];
            float av = alsb[s * 4 + h] + aldh;
            av = av > 0.f ? av : SLOPE * av;
            al = __expf(av) * inv;
            aEb[csr_opos[k]] = al;   // alpha emitted directly in out-CSR order
        }
        salp[g][j] = al;
        if (h == 0) ssrc[g][t8] = s;
        __builtin_amdgcn_wave_barrier();
#pragma unroll
        for (int t = 0; t < 8; t++)
            acc += salp[g][(h << 3) + t] * xpb[ssrc[g][t] * 32 + j];
        __builtin_amdgcn_wave_barrier();
    }
    float y = h1[idx * 32 + j] + acc + sb[j];
    float mean = red32(y) * (1.f / 32.f);
    float d0 = y - mean;
    float var = red32(d0 * d0) * (1.f / 32.f);
    outH[idx * 32 + j] = d0 * rsqrtf(var + EPSL) * sg[j] + sbt[j];
}

// ------- K4: compose A rows in LDS (one wave per row), stream out --------
#define ROWS_PER_BLOCK 4
__global__ __launch_bounds__(256) void k_rowA(
    const int* __restrict__ off2, const int* __restrict__ out_dst,
    const float* __restrict__ alphaE, float* __restrict__ A) {
    __shared__ float sRow[ROWS_PER_BLOCK][NN];
    int wid = threadIdx.x >> 6, lane = threadIdx.x & 63;
    int r = blockIdx.x * ROWS_PER_BLOCK + wid;   // (b*4+h)*1024 + src
    int bh = r >> 10, src = r & 1023;
    float4* row4 = (float4*)&sRow[wid][0];
    float4 z = make_float4(0.f, 0.f, 0.f, 0.f);
#pragma unroll
    for (int i = 0; i < 4; i++) row4[i * 64 + lane] = z;
    __builtin_amdgcn_wave_barrier();
    int beg = off2[src], end = off2[src + 1];
    const float* aE = alphaE + (size_t)bh * EE;
    for (int p = beg + lane; p < end; p += 64)
        sRow[wid][out_dst[p]] = aE[p];           // contiguous reads now
    __builtin_amdgcn_wave_barrier();
    float4* o4 = (float4*)(A + (size_t)bh * (NN * NN) + (size_t)src * NN);
#pragma unroll
    for (int i = 0; i < 4; i++) o4[i * 64 + lane] = row4[i * 64 + lane];
}

extern "C" void kernel_launch(void* const* d_in, const int* in_sizes, int n_in,
                              void* d_out, int out_size, void* d_ws, size_t ws_size,
                              hipStream_t stream) {
    const float* Hm  = (const float*)d_in[0];
    const int*   ei  = (const int*)d_in[1];
    const float* W1  = (const float*)d_in[2];
    const float* b1  = (const float*)d_in[3];
    const float* W2  = (const float*)d_in[4];
    const float* b2  = (const float*)d_in[5];
    const float* lneg = (const float*)d_in[6];
    const float* lneb = (const float*)d_in[7];
    const float* Wg1 = (const float*)d_in[8];
    const float* as1 = (const float*)d_in[9];
    const float* ad1 = (const float*)d_in[10];
    const float* bi1 = (const float*)d_in[11];
    const float* Wg2 = (const float*)d_in[12];
    const float* as2 = (const float*)d_in[13];
    const float* ad2 = (const float*)d_in[14];
    const float* bi2 = (const float*)d_in[15];
    const float* lnog = (const float*)d_in[16];
    const float* lnob = (const float*)d_in[17];

    float* outH = (float*)d_out;                 // [B,N,32]
    float* A    = outH + BB * NN * FF;           // [B,4,N,N]

    // workspace carve
    int* deg      = (int*)d_ws;          // 1024
    int* off      = deg + 1024;          // 1028 (1025 used)
    int* cur      = off + 1028;          // 1024
    int* deg2     = cur + 1024;          // 1024
    int* off2     = deg2 + 1024;         // 1028
    int* cur2     = off2 + 1028;         // 1024
    int* csr_src  = cur2 + 1024;         // 32768
    int* csr_opos = csr_src + EE;        // 32768
    int* out_dst  = csr_opos + EE;       // 32768
    float* fb     = (float*)(out_dst + EE);
    float* xp1    = fb;                  // 524288
    float* als1   = xp1 + BB * NN * FF;  // 65536
    float* ald1   = als1 + BB * NN * 4;  // 65536
    float* h1     = ald1 + BB * NN * 4;  // 524288
    float* xp2    = h1 + BB * NN * FF;   // 524288
    float* als2   = xp2 + BB * NN * FF;  // 65536
    float* ald2   = als2 + BB * NN * 4;  // 65536
    float* alphaE = ald2 + BB * NN * 4;  // 2097152 (B*H*E)

    hipLaunchKernelGGL(k_init, dim3(1), dim3(256), 0, stream, deg, deg2);
    hipLaunchKernelGGL(k_count, dim3(EE / 256), dim3(256), 0, stream, ei, deg, deg2);
    hipLaunchKernelGGL(k_scan, dim3(1), dim3(1024), 0, stream,
                       deg, off, cur, deg2, off2, cur2);
    hipLaunchKernelGGL(k_fill, dim3(EE / 256), dim3(256), 0, stream,
                       ei, cur, csr_src, cur2, out_dst, csr_opos);
    hipLaunchKernelGGL(k_embed, dim3(BB * NN / 8), dim3(256), 0, stream,
                       Hm, W1, b1, W2, b2, lneg, lneb, Wg1, as1, ad1,
                       xp1, als1, ald1);
    hipLaunchKernelGGL(k_gat1, dim3(BB * NN / 8), dim3(256), 0, stream,
                       off, csr_src, xp1, als1, ald1, bi1, Wg2, as2, ad2,
                       h1, xp2, als2, ald2);
    hipLaunchKernelGGL(k_gat2, dim3(BB * NN / 8), dim3(256), 0, stream,
                       off, csr_src, csr_opos, xp2, als2, ald2, h1, bi2, lnog, lnob,
                       outH, alphaE);
    hipLaunchKernelGGL(k_rowA, dim3(BB * HEADS * NN / ROWS_PER_BLOCK), dim3(256),
                       0, stream, off2, out_dst, alphaE, A);
}